// Round 11
// baseline (633.370 us; speedup 1.0000x reference)
//
#include <hip/hip_runtime.h>
#include <hip/hip_bf16.h>
#include <stdint.h>

// TreeLSTM fused, round 11: R10 (W resident in registers) with the kh-range
// bug fixed (xa[16] covers full K=256) and register surgery to fit 256 VGPR:
// biases loaded into acc at tile start (no bias regs, no epilogue adds),
// x packed inline in the MFMA loop.
// Wave = 1 slice (16 cols) x 4 gates: wreg = 128 VGPR loaded once.
// Block = 512 thr (8 waves = half width); blocks b, b+128 pair on one XCD
// (128%8==0) and read the same x rows -> x HBM-fetched once, L2-shared.
// Per tile: 4 bias(L1) + 16 x + 4 Uh/fc loads, 32 MFMA, 3 nt stores.
// All HBM loads issued a full phase before consumption. No LDS, no barriers.

typedef __attribute__((ext_vector_type(8))) short bf16x8;
typedef __attribute__((ext_vector_type(4))) float f4v;

#define N_ROWS 200000
#define TILES 12500     // N_ROWS / 16
#define NBLK 256        // 128 row-phases x 2 halves
#define SBAR() __builtin_amdgcn_sched_barrier(0)

__device__ __forceinline__ bf16x8 pack8(f4v a, f4v b) {
    union { __hip_bfloat162 h2[4]; bf16x8 v; } u;
    u.h2[0] = __float22bfloat162_rn(make_float2(a.x, a.y));
    u.h2[1] = __float22bfloat162_rn(make_float2(a.z, a.w));
    u.h2[2] = __float22bfloat162_rn(make_float2(b.x, b.y));
    u.h2[3] = __float22bfloat162_rn(make_float2(b.z, b.w));
    return u.v;
}
__device__ __forceinline__ float fsig(float x) { return 1.0f / (1.0f + __expf(-x)); }
__device__ __forceinline__ float ftanh(float x) {
    float e = __expf(2.0f * x);
    return 1.0f - 2.0f / (e + 1.0f);
}

__global__ __launch_bounds__(512, 2)
void treelstm_main(const float* __restrict__ x,
                   const float* __restrict__ Uh,
                   const float* __restrict__ fc,
                   const float* __restrict__ W_iou,
                   const float* __restrict__ b_iou,
                   const float* __restrict__ W_f,
                   const float* __restrict__ b_f,
                   float* __restrict__ out) {
    const int tid  = threadIdx.x;
    const int lane = tid & 63;
    const int w    = tid >> 6;              // wave 0..7
    const int q    = lane >> 4;
    const int bcol = lane & 15;
    const int half = blockIdx.x >> 7;       // width half
    const int boff = blockIdx.x & 127;      // row phase
    const int sl   = half * 8 + w;          // global slice 0..15
    const int kb   = sl * 16 + q * 4;       // lane's 4 output cols (per gate)
    const int C    = sl * 16 + bcol;        // W row for A-frag

    // ---- resident W fragments: wreg[g*8+ks], loaded ONCE (128 VGPR) ----
    // A-frag: A[row = lane&15 -> W-col C][k = ks*32 + q*8 + 0..7]
    bf16x8 wreg[32];
#pragma unroll
    for (int g = 0; g < 4; ++g) {
        const float* wr = (g < 3) ? (W_iou + (size_t)(g * 256 + C) * 256)
                                  : (W_f + (size_t)C * 256);
#pragma unroll
        for (int ks = 0; ks < 8; ++ks) {
            const f4v p0 = *(const f4v*)(wr + ks * 32 + q * 8);
            const f4v p1 = *(const f4v*)(wr + ks * 32 + q * 8 + 4);
            wreg[g * 8 + ks] = pack8(p0, p1);
        }
    }

    float* out_h = out;
    float* out_c = out + (size_t)N_ROWS * 256;
    float* out_f = out + 2 * (size_t)N_ROWS * 256;

    // ---- prologue: issue first tile's loads (x full K, then Uh/fc) ----
    int t = boff;
    f4v xa[16];
    f4v uhi, uho, uhu, fcv;
    {
        const float* xb = x + (size_t)(t * 16 + bcol) * 256 + q * 8;
#pragma unroll
        for (int k2 = 0; k2 < 8; ++k2) {
            xa[2 * k2]     = *(const f4v*)(xb + k2 * 32);
            xa[2 * k2 + 1] = *(const f4v*)(xb + k2 * 32 + 4);
        }
        const float* uh = Uh + (size_t)(t * 16 + bcol) * 768 + kb;
        uhi = __builtin_nontemporal_load((const f4v*)uh);
        uho = __builtin_nontemporal_load((const f4v*)(uh + 256));
        uhu = __builtin_nontemporal_load((const f4v*)(uh + 512));
        fcv = __builtin_nontemporal_load((const f4v*)(fc + (size_t)(t * 16 + bcol) * 256 + kb));
    }

    while (true) {
        const int n = t * 16 + bcol;

        // ---- acc init = biases (L1-hot loads; drain waits only older loads,
        //      all of which are needed before/at MFMA anyway) ----
        f4v acc[4];
        acc[0] = *(const f4v*)&b_iou[kb];
        acc[1] = *(const f4v*)&b_iou[256 + kb];
        acc[2] = *(const f4v*)&b_iou[512 + kb];
        acc[3] = *(const f4v*)&b_f[kb];

        // ---- MFMA, packing x inline (consumes xa; zero other memory ops) ----
#pragma unroll
        for (int ks = 0; ks < 8; ++ks) {
            const bf16x8 xf = pack8(xa[2 * ks], xa[2 * ks + 1]);
            acc[0] = __builtin_amdgcn_mfma_f32_16x16x32_bf16(wreg[0 * 8 + ks], xf, acc[0], 0, 0, 0);
            acc[1] = __builtin_amdgcn_mfma_f32_16x16x32_bf16(wreg[1 * 8 + ks], xf, acc[1], 0, 0, 0);
            acc[2] = __builtin_amdgcn_mfma_f32_16x16x32_bf16(wreg[2 * 8 + ks], xf, acc[2], 0, 0, 0);
            acc[3] = __builtin_amdgcn_mfma_f32_16x16x32_bf16(wreg[3 * 8 + ks], xf, acc[3], 0, 0, 0);
        }
        SBAR();

        // ---- prefetch next tile's x (full K); flies through epilogue ----
        const int tn = t + 128;
        const bool more = (tn < TILES);
        if (more) {
            const float* xb = x + (size_t)(tn * 16 + bcol) * 256 + q * 8;
#pragma unroll
            for (int k2 = 0; k2 < 8; ++k2) {
                xa[2 * k2]     = *(const f4v*)(xb + k2 * 32);
                xa[2 * k2 + 1] = *(const f4v*)(xb + k2 * 32 + 4);
            }
        }
        SBAR();

        // ---- epilogue: waits Uh/fc(t) only (x(tn) younger, stays in flight) ----
        f4v cc, hh, ff;
        cc.x = fsig(acc[0].x + uhi.x) * ftanh(acc[2].x + uhu.x) + fcv.x;
        cc.y = fsig(acc[0].y + uhi.y) * ftanh(acc[2].y + uhu.y) + fcv.y;
        cc.z = fsig(acc[0].z + uhi.z) * ftanh(acc[2].z + uhu.z) + fcv.z;
        cc.w = fsig(acc[0].w + uhi.w) * ftanh(acc[2].w + uhu.w) + fcv.w;
        hh.x = fsig(acc[1].x + uho.x) * ftanh(cc.x);
        hh.y = fsig(acc[1].y + uho.y) * ftanh(cc.y);
        hh.z = fsig(acc[1].z + uho.z) * ftanh(cc.z);
        hh.w = fsig(acc[1].w + uho.w) * ftanh(cc.w);
        ff.x = acc[3].x;
        ff.y = acc[3].y;
        ff.z = acc[3].z;
        ff.w = acc[3].w;
        const size_t oidx = (size_t)n * 256 + kb;
        __builtin_nontemporal_store(hh, (f4v*)(out_h + oidx));
        __builtin_nontemporal_store(cc, (f4v*)(out_c + oidx));
        __builtin_nontemporal_store(ff, (f4v*)(out_f + oidx));

        if (!more) break;
        SBAR();

        // ---- issue next tile's Uh/fc (after x(tn): in-order discipline) ----
        const float* uh = Uh + (size_t)(tn * 16 + bcol) * 768 + kb;
        uhi = __builtin_nontemporal_load((const f4v*)uh);
        uho = __builtin_nontemporal_load((const f4v*)(uh + 256));
        uhu = __builtin_nontemporal_load((const f4v*)(uh + 512));
        fcv = __builtin_nontemporal_load((const f4v*)(fc + (size_t)(tn * 16 + bcol) * 256 + kb));
        t = tn;
    }
}

extern "C" void kernel_launch(void* const* d_in, const int* in_sizes, int n_in,
                              void* d_out, int out_size, void* d_ws, size_t ws_size,
                              hipStream_t stream) {
    const float* x     = (const float*)d_in[0];
    const float* Uh    = (const float*)d_in[1];
    const float* fc    = (const float*)d_in[2];
    const float* W_iou = (const float*)d_in[3];
    const float* b_iou = (const float*)d_in[4];
    const float* W_f   = (const float*)d_in[5];
    const float* b_f   = (const float*)d_in[6];
    float* out = (float*)d_out;

    treelstm_main<<<NBLK, 512, 0, stream>>>(x, Uh, fc, W_iou, b_iou, W_f, b_f, out);
}

// Round 12
// 418.657 us; speedup vs baseline: 1.5129x; 1.5129x over previous
//
#include <hip/hip_runtime.h>
#include <hip/hip_bf16.h>
#include <stdint.h>

// TreeLSTM fused, round 12: W resident in regs (forced via waves_per_eu(2,2)),
// x staged to LDS via global_load_lds (VGPR-free in-flight buffer), counted
// vmcnt + raw s_barrier pipeline so loads stay in flight across the barrier.
// Block = 512 thr (8 waves = 8 slices = half width), 256 blocks; blocks b and
// b+128 pair on one XCD (same x rows -> single HBM fetch, L2-shared).
// Per wave per tile: 2 stage + 4 Uh/fc loads, 16 ds_read_b128, 32 MFMA,
// 3 nt stores, 1 barrier. vmcnt(7) at tile end drains exactly the 2 stage
// loads; Uh/fc and stores stay outstanding.

typedef __attribute__((ext_vector_type(8))) short bf16x8;
typedef __attribute__((ext_vector_type(4))) float f4v;

#define N_ROWS 200000
#define TILES 12500     // N_ROWS / 16
#define XSTR 258        // LDS row stride in floats (256 + 2) -> conflict-free

__device__ __forceinline__ bf16x8 pack8(f4v a, f4v b) {
    union { __hip_bfloat162 h2[4]; bf16x8 v; } u;
    u.h2[0] = __float22bfloat162_rn(make_float2(a.x, a.y));
    u.h2[1] = __float22bfloat162_rn(make_float2(a.z, a.w));
    u.h2[2] = __float22bfloat162_rn(make_float2(b.x, b.y));
    u.h2[3] = __float22bfloat162_rn(make_float2(b.z, b.w));
    return u.v;
}
__device__ __forceinline__ float fsig(float x) { return 1.0f / (1.0f + __expf(-x)); }
__device__ __forceinline__ float ftanh(float x) {
    float e = __expf(2.0f * x);
    return 1.0f - 2.0f / (e + 1.0f);
}

__global__ __launch_bounds__(512)
__attribute__((amdgpu_waves_per_eu(2, 2)))
void treelstm_main(const float* __restrict__ x,
                   const float* __restrict__ Uh,
                   const float* __restrict__ fc,
                   const float* __restrict__ W_iou,
                   const float* __restrict__ b_iou,
                   const float* __restrict__ W_f,
                   const float* __restrict__ b_f,
                   float* __restrict__ out) {
    __shared__ float xlds[2][16 * XSTR];     // 33 KB, double-buffered x tile

    const int tid   = threadIdx.x;
    const int lane  = tid & 63;
    const int w     = tid >> 6;              // wave 0..7
    const int q     = lane >> 4;
    const int bcol  = lane & 15;
    const int half  = blockIdx.x >> 7;       // width half (b, b+128 same XCD)
    const int phase = blockIdx.x & 127;      // row phase
    const int sl    = half * 8 + w;          // global slice 0..15
    const int kb    = sl * 16 + q * 4;       // lane's 4 output cols per gate
    const int C     = sl * 16 + bcol;        // W row for A-frag

    // ---- resident biases (16 VGPR) ----
    const f4v bi  = *(const f4v*)&b_iou[kb];
    const f4v bo  = *(const f4v*)&b_iou[256 + kb];
    const f4v bu  = *(const f4v*)&b_iou[512 + kb];
    const f4v bf4 = *(const f4v*)&b_f[kb];

    // ---- resident W fragments (128 VGPR), loaded once ----
    // A-frag: A[row = lane&15 -> W-col C][k = ks*32 + q*8 + 0..7]
    bf16x8 wreg[32];
#pragma unroll
    for (int g = 0; g < 4; ++g) {
        const float* wr = (g < 3) ? (W_iou + (size_t)(g * 256 + C) * 256)
                                  : (W_f + (size_t)C * 256);
#pragma unroll
        for (int ks = 0; ks < 8; ++ks) {
            const f4v p0 = *(const f4v*)(wr + ks * 32 + q * 8);
            const f4v p1 = *(const f4v*)(wr + ks * 32 + q * 8 + 4);
            wreg[g * 8 + ks] = pack8(p0, p1);
        }
    }

    float* out_h = out;
    float* out_c = out + (size_t)N_ROWS * 256;
    float* out_f = out + 2 * (size_t)N_ROWS * 256;

    // stage tile t's x into LDS buf: wave w stages rows 2w, 2w+1 (2 x 1KB)
    auto STAGE = [&](int t, int buf) {
#pragma unroll
        for (int rr = 0; rr < 2; ++rr) {
            const int r = 2 * w + rr;
            const float* src = x + (size_t)(t * 16 + r) * 256 + lane * 4;
            __builtin_amdgcn_global_load_lds(
                (const __attribute__((address_space(1))) uint32_t*)src,
                (__attribute__((address_space(3))) uint32_t*)&xlds[buf][r * XSTR],
                16, 0, 0);
        }
        __builtin_amdgcn_sched_barrier(0);
    };

    f4v uhi, uho, uhu, fcv;
    auto LOADUH = [&](int tt) {
        const float* uh = Uh + (size_t)(tt * 16 + bcol) * 768 + kb;
        uhi = __builtin_nontemporal_load((const f4v*)uh);
        uho = __builtin_nontemporal_load((const f4v*)(uh + 256));
        uhu = __builtin_nontemporal_load((const f4v*)(uh + 512));
        fcv = __builtin_nontemporal_load((const f4v*)(fc + (size_t)(tt * 16 + bcol) * 256 + kb));
    };

    // ---- prologue ----
    int t = phase, buf = 0;
    STAGE(t, 0);
    LOADUH(t);
    asm volatile("s_waitcnt vmcnt(4)" ::: "memory");   // x(t) in LDS; uh in flight
    __builtin_amdgcn_s_barrier();
    __builtin_amdgcn_sched_barrier(0);

    while (true) {
        const int tn = t + 128;
        const bool more = (tn < TILES);
        if (more) STAGE(tn, buf ^ 1);       // safe: no wave reads buf^1 anymore

        // ---- MFMA from LDS (acc = bias-init); pack inline ----
        f4v acc0 = bi, acc1 = bo, acc2 = bu, acc3 = bf4;
#pragma unroll
        for (int ks = 0; ks < 8; ++ks) {
            const f4v p0 = *(const f4v*)&xlds[buf][bcol * XSTR + ks * 32 + q * 8];
            const f4v p1 = *(const f4v*)&xlds[buf][bcol * XSTR + ks * 32 + q * 8 + 4];
            const bf16x8 xf = pack8(p0, p1);
            acc0 = __builtin_amdgcn_mfma_f32_16x16x32_bf16(wreg[0 * 8 + ks], xf, acc0, 0, 0, 0);
            acc1 = __builtin_amdgcn_mfma_f32_16x16x32_bf16(wreg[1 * 8 + ks], xf, acc1, 0, 0, 0);
            acc2 = __builtin_amdgcn_mfma_f32_16x16x32_bf16(wreg[2 * 8 + ks], xf, acc2, 0, 0, 0);
            acc3 = __builtin_amdgcn_mfma_f32_16x16x32_bf16(wreg[3 * 8 + ks], xf, acc3, 0, 0, 0);
        }

        // ---- epilogue: compiler drains uh(t) only (stage(tn) stays in flight) ----
        const int n = t * 16 + bcol;
        f4v cc, hh, ff;
        cc.x = fsig(acc0.x + uhi.x) * ftanh(acc2.x + uhu.x) + fcv.x;
        cc.y = fsig(acc0.y + uhi.y) * ftanh(acc2.y + uhu.y) + fcv.y;
        cc.z = fsig(acc0.z + uhi.z) * ftanh(acc2.z + uhu.z) + fcv.z;
        cc.w = fsig(acc0.w + uhi.w) * ftanh(acc2.w + uhu.w) + fcv.w;
        hh.x = fsig(acc1.x + uho.x) * ftanh(cc.x);
        hh.y = fsig(acc1.y + uho.y) * ftanh(cc.y);
        hh.z = fsig(acc1.z + uho.z) * ftanh(cc.z);
        hh.w = fsig(acc1.w + uho.w) * ftanh(cc.w);
        ff.x = acc3.x; ff.y = acc3.y; ff.z = acc3.z; ff.w = acc3.w;
        const size_t oidx = (size_t)n * 256 + kb;
        __builtin_nontemporal_store(hh, (f4v*)(out_h + oidx));
        __builtin_nontemporal_store(cc, (f4v*)(out_c + oidx));
        __builtin_nontemporal_store(ff, (f4v*)(out_f + oidx));

        if (!more) break;

        LOADUH(tn);                          // uh(t+1): flies across the barrier
        // drain EXACTLY the 2 stage loads (oldest); stores + uh stay in flight
        asm volatile("s_waitcnt vmcnt(7)" ::: "memory");
        __builtin_amdgcn_s_barrier();
        __builtin_amdgcn_sched_barrier(0);
        t = tn; buf ^= 1;
    }
}

extern "C" void kernel_launch(void* const* d_in, const int* in_sizes, int n_in,
                              void* d_out, int out_size, void* d_ws, size_t ws_size,
                              hipStream_t stream) {
    const float* x     = (const float*)d_in[0];
    const float* Uh    = (const float*)d_in[1];
    const float* fc    = (const float*)d_in[2];
    const float* W_iou = (const float*)d_in[3];
    const float* b_iou = (const float*)d_in[4];
    const float* W_f   = (const float*)d_in[5];
    const float* b_f   = (const float*)d_in[6];
    float* out = (float*)d_out;

    treelstm_main<<<256, 512, 0, stream>>>(x, Uh, fc, W_iou, b_iou, W_f, b_f, out);
}